// Round 4
// baseline (280.271 us; speedup 1.0000x reference)
//
#include <hip/hip_runtime.h>
#include <hip/hip_bf16.h>

#define NN   100000
#define DD   128
#define ZZ   128
#define TT   1024
#define KK   256
#define HIDD 512

typedef __attribute__((ext_vector_type(8))) short  short8;   // 8 bf16 (MFMA A/B frag)
typedef __attribute__((ext_vector_type(4))) float  f32x4;    // MFMA C/D frag

__device__ inline unsigned short f2bf(float f) {  // RTNE fp32 -> bf16
    union { float f; unsigned int u; } x; x.f = f;
    unsigned int r = x.u + 0x7fffu + ((x.u >> 16) & 1u);
    return (unsigned short)(r >> 16);
}
__device__ inline void load_lds16(const void* g, void* l) {
    __builtin_amdgcn_global_load_lds((const __attribute__((address_space(1))) unsigned int*)g,
                                     (__attribute__((address_space(3))) unsigned int*)l, 16, 0, 0);
}

// ---------------- Kernel 1: zpe = z + pe@W_pe (bf16), ctx cast to bf16 — 8 elems/thread ----------------
__global__ __launch_bounds__(256) void prep_tables(
    const float* __restrict__ pe, const float* __restrict__ ctx,
    const float* __restrict__ z, const float* __restrict__ wpe,
    unsigned short* __restrict__ ctx_bf, unsigned short* __restrict__ zpe_bf) {
    int g = blockIdx.x * 256 + threadIdx.x;      // one thread per 8 elements
    if (g >= NN * 16) return;
    int n = g >> 4, j8 = (g & 15) << 3;
    float p0 = pe[n * 4 + 0], p1 = pe[n * 4 + 1], p2 = pe[n * 4 + 2], p3 = pe[n * 4 + 3];
    float4 c0 = *(const float4*)(ctx + (size_t)n * 128 + j8);
    float4 c1 = *(const float4*)(ctx + (size_t)n * 128 + j8 + 4);
    float4 z0 = *(const float4*)(z + j8);
    float4 z1 = *(const float4*)(z + j8 + 4);
    float4 wa0 = *(const float4*)(wpe + 0 * ZZ + j8), wa1 = *(const float4*)(wpe + 0 * ZZ + j8 + 4);
    float4 wb0 = *(const float4*)(wpe + 1 * ZZ + j8), wb1 = *(const float4*)(wpe + 1 * ZZ + j8 + 4);
    float4 wc0 = *(const float4*)(wpe + 2 * ZZ + j8), wc1 = *(const float4*)(wpe + 2 * ZZ + j8 + 4);
    float4 wd0 = *(const float4*)(wpe + 3 * ZZ + j8), wd1 = *(const float4*)(wpe + 3 * ZZ + j8 + 4);
    float zp[8], cv[8];
    zp[0] = z0.x + p0 * wa0.x + p1 * wb0.x + p2 * wc0.x + p3 * wd0.x;
    zp[1] = z0.y + p0 * wa0.y + p1 * wb0.y + p2 * wc0.y + p3 * wd0.y;
    zp[2] = z0.z + p0 * wa0.z + p1 * wb0.z + p2 * wc0.z + p3 * wd0.z;
    zp[3] = z0.w + p0 * wa0.w + p1 * wb0.w + p2 * wc0.w + p3 * wd0.w;
    zp[4] = z1.x + p0 * wa1.x + p1 * wb1.x + p2 * wc1.x + p3 * wd1.x;
    zp[5] = z1.y + p0 * wa1.y + p1 * wb1.y + p2 * wc1.y + p3 * wd1.y;
    zp[6] = z1.z + p0 * wa1.z + p1 * wb1.z + p2 * wc1.z + p3 * wd1.z;
    zp[7] = z1.w + p0 * wa1.w + p1 * wb1.w + p2 * wc1.w + p3 * wd1.w;
    cv[0] = c0.x; cv[1] = c0.y; cv[2] = c0.z; cv[3] = c0.w;
    cv[4] = c1.x; cv[5] = c1.y; cv[6] = c1.z; cv[7] = c1.w;
    short8 sz, sc;
#pragma unroll
    for (int i = 0; i < 8; ++i) { sz[i] = (short)f2bf(zp[i]); sc[i] = (short)f2bf(cv[i]); }
    *(short8*)(zpe_bf + (size_t)g * 8) = sz;
    *(short8*)(ctx_bf + (size_t)g * 8) = sc;
}

// ---------------- Kernel 2: pack W1(k<256)/W2 into MFMA frag order  +  ct = b1 + z_tgt@W1c ----------------
// Frag tile (16 out x 32 k): lane l elem e -> k_local = (l>>4)*8 + e, out = l&15.
// Blocks 0..767: packing. Blocks 768..895: ct for 8 targets each (z_tgt computed from pe directly).
__global__ __launch_bounds__(256) void pack_ct(
    const float* __restrict__ W1, const float* __restrict__ W2,
    const float* __restrict__ pe, const float* __restrict__ z, const float* __restrict__ wpe,
    const int* __restrict__ target_nodes, const float* __restrict__ b1,
    unsigned short* __restrict__ w1p, unsigned short* __restrict__ w2p, float* __restrict__ ct_g) {
    __shared__ float zp[8][128];
    int tid = threadIdx.x;
    if (blockIdx.x < 768) {
        int g = blockIdx.x * 256 + tid;
        if (g < 256 * HIDD) {                         // W1 rows 0..255 (ctx|zpe parts)
            int e = g & 7, l = (g >> 3) & 63, tile = g >> 9;
            int ntg = tile & 7, rem = tile >> 3;      // rem = hc*8 + kc
            int kc = rem & 7, hc = rem >> 3;
            int k = kc * 32 + (l >> 4) * 8 + e;
            int n = hc * 128 + ntg * 16 + (l & 15);
            w1p[g] = f2bf(W1[(size_t)k * HIDD + n]);
        } else {
            int q = g - 256 * HIDD;
            int e = q & 7, l = (q >> 3) & 63, tile = q >> 9;
            int ntg = tile & 7, kcg = tile >> 3;
            int k = kcg * 32 + (l >> 4) * 8 + e;
            int n = ntg * 16 + (l & 15);
            w2p[q] = f2bf(W2[(size_t)k * DD + n]);
        }
        return;
    }
    int b = blockIdx.x - 768;                         // 0..127, 8 targets each
#pragma unroll
    for (int q = 0; q < 4; ++q) {
        int idx = q * 256 + tid;                      // 0..1023
        int t8 = idx >> 7, zz = idx & 127;
        int tgt = target_nodes[b * 8 + t8];
        zp[t8][zz] = z[zz] + pe[tgt * 4 + 0] * wpe[zz] + pe[tgt * 4 + 1] * wpe[128 + zz]
                           + pe[tgt * 4 + 2] * wpe[256 + zz] + pe[tgt * 4 + 3] * wpe[384 + zz];
    }
    __syncthreads();
    int j0 = tid, j1 = tid + 256;
    float a0[8], a1[8];
    float bb0 = b1[j0], bb1 = b1[j1];
#pragma unroll
    for (int t8 = 0; t8 < 8; ++t8) { a0[t8] = bb0; a1[t8] = bb1; }
#pragma unroll 8
    for (int zz = 0; zz < 128; ++zz) {
        float w0 = W1[(size_t)(256 + zz) * HIDD + j0];
        float w1 = W1[(size_t)(256 + zz) * HIDD + j1];
#pragma unroll
        for (int t8 = 0; t8 < 8; ++t8) { a0[t8] += zp[t8][zz] * w0; a1[t8] += zp[t8][zz] * w1; }
    }
#pragma unroll
    for (int t8 = 0; t8 < 8; ++t8) {
        ct_g[(size_t)(b * 8 + t8) * HIDD + j0] = a0[t8];
        ct_g[(size_t)(b * 8 + t8) * HIDD + j1] = a1[t8];
    }
}

// ---------------- Kernel 3: fused gather + MLP + masked-MSE ----------------
// Block = (target t, 64-row K-tile). 4 waves. HID in 4 chunks of 128.
// GEMM1 computes h^T via swapped MFMA operands: mfma(W1frag, aggfrag) -> lane holds
// 4 consecutive h-cols of one agg-row -> b64 hT writes, conflict-free with ^((row&7)<<4).
// Weights register-preloaded per hc; inner loops are pure LDS+MFMA.
__global__ __launch_bounds__(256) void mp_jepa_main(
    const unsigned short* __restrict__ ctx_bf,
    const unsigned short* __restrict__ zpe_bf,
    const unsigned short* __restrict__ w1p,
    const unsigned short* __restrict__ w2p,
    const float* __restrict__ ct_g,
    const float* __restrict__ target_embedding,
    const int* __restrict__ sub_nodes,
    const int* __restrict__ sub_counts,
    const int* __restrict__ target_nodes,
    const float* __restrict__ b2,
    float* __restrict__ out) {
    const int bid = blockIdx.x;
    const int t = bid >> 2, kt = bid & 3;
    const int k0 = kt * 64;
    int cnt = sub_counts[t]; if (cnt < 1) cnt = 1;
    if (k0 >= cnt) return;           // uniform early-exit before any barrier
    const int tgt = target_nodes[t];

    __shared__ __align__(16) unsigned short ctxT[64 * 128];  // 16 KB, swizzled ^((row&7)<<4)
    __shared__ __align__(16) unsigned short zpeT[64 * 128];  // 16 KB, swizzled
    __shared__ __align__(16) unsigned short hT[64 * 128];    // 16 KB, swizzled
    __shared__ float cts[HIDD];
    __shared__ float tgte[DD];
    __shared__ float b2s[DD];
    __shared__ float red[4];

    const int tid = threadIdx.x;
    const int w = tid >> 6, l = tid & 63;
    const int lo = l & 15, hi = l >> 4;

    // Async gather: linear LDS dest (base + lane*16), inverse-swizzled global source.
    {
        const char* cc = (const char*)ctx_bf;
        const char* zc = (const char*)zpe_bf;
        const int base = t * KK + k0;
#pragma unroll
        for (int it = 0; it < 4; ++it) {
            int rgrp = it * 16 + (w << 2);        // wave-uniform row-group base (4 rows)
            int row  = rgrp + hi;
            int node = sub_nodes[base + row];
            int soff = (lo << 4) ^ ((row & 7) << 4);
            load_lds16(cc + (size_t)node * 256 + soff, (char*)ctxT + rgrp * 256);
            load_lds16(zc + (size_t)node * 256 + soff, (char*)zpeT + rgrp * 256);
        }
    }
    // params load overlaps the in-flight gather
    if (tid < 128) {
        tgte[tid] = target_embedding[(size_t)tgt * 128 + tid];
        b2s[tid]  = b2[tid];
    }
    cts[tid]       = ct_g[(size_t)t * HIDD + tid];
    cts[tid + 256] = ct_g[(size_t)t * HIDD + tid + 256];
    __syncthreads();

    const short8* w1v = (const short8*)w1p;
    const short8* w2v = (const short8*)w2p;

    f32x4 accP[4][2];
#pragma unroll
    for (int rg = 0; rg < 4; ++rg)
#pragma unroll
        for (int nt = 0; nt < 2; ++nt) accP[rg][nt] = (f32x4){0.f, 0.f, 0.f, 0.f};

    for (int hc = 0; hc < 4; ++hc) {
        // ---- preload all W1 frags for this hc (16 x 16B, independent L2 loads)
        short8 wA[16];
#pragma unroll
        for (int i = 0; i < 16; ++i) {
            int kc = i >> 1, nt = i & 1;
            wA[i] = w1v[((((hc << 3) + kc) << 3) + (w << 1) + nt) * 64 + l];
        }
        // ---- GEMM1 (transposed): acc1[rg][nt] = h^T tile [hcol-tile=(w*2+nt)][aggrow-tile=rg]
        f32x4 acc1[4][2];
#pragma unroll
        for (int nt = 0; nt < 2; ++nt) {
            f32x4 cv = *(const f32x4*)&cts[(hc << 7) + (((w << 1) + nt) << 4) + (hi << 2)];
#pragma unroll
            for (int rg = 0; rg < 4; ++rg) acc1[rg][nt] = cv;
        }
#pragma unroll
        for (int kc = 0; kc < 8; ++kc) {
            const unsigned short* src = (kc < 4) ? ctxT : zpeT;
            int cb = ((kc & 3) << 6) + (hi << 4);
            short8 a[4];
#pragma unroll
            for (int rg = 0; rg < 4; ++rg) {
                int row = (rg << 4) + lo;
                a[rg] = *(const short8*)(src + ((row * 256 + (cb ^ ((row & 7) << 4))) >> 1));
            }
#pragma unroll
            for (int rg = 0; rg < 4; ++rg) {
                acc1[rg][0] = __builtin_amdgcn_mfma_f32_16x16x32_bf16(wA[(kc << 1) + 0], a[rg], acc1[rg][0], 0, 0, 0);
                acc1[rg][1] = __builtin_amdgcn_mfma_f32_16x16x32_bf16(wA[(kc << 1) + 1], a[rg], acc1[rg][1], 0, 0, 0);
            }
        }

        // ---- preload W2 frags for this hc (issued before write phase; latency hidden)
        short8 wB[8];
#pragma unroll
        for (int i = 0; i < 8; ++i) {
            int kc2 = i >> 1, nt = i & 1;
            wB[i] = w2v[((((hc << 2) + kc2) << 3) + (w << 1) + nt) * 64 + l];
        }

        __syncthreads();  // prior GEMM2 finished reading hT
        // relu -> bf16 -> hT: each lane writes 4 consecutive h-cols of one agg-row (b64)
#pragma unroll
        for (int nt = 0; nt < 2; ++nt) {
            int cbase = (((w << 1) + nt) << 5) + (hi << 3);   // byte offset of 4 h-cols
#pragma unroll
            for (int rg = 0; rg < 4; ++rg) {
                int row = (rg << 4) + lo;
                f32x4 v = acc1[rg][nt];
                float v0 = v[0] > 0.f ? v[0] : 0.f;
                float v1 = v[1] > 0.f ? v[1] : 0.f;
                float v2 = v[2] > 0.f ? v[2] : 0.f;
                float v3 = v[3] > 0.f ? v[3] : 0.f;
                uint2 p;
                p.x = (unsigned int)f2bf(v0) | ((unsigned int)f2bf(v1) << 16);
                p.y = (unsigned int)f2bf(v2) | ((unsigned int)f2bf(v3) << 16);
                *(uint2*)((char*)hT + row * 256 + (cbase ^ ((row & 7) << 4))) = p;
            }
        }
        __syncthreads();

        // ---- GEMM2 partial: pred += relu_h[64,128] @ W2[hc*128.., 128]
#pragma unroll
        for (int kc2 = 0; kc2 < 4; ++kc2) {
            int cb = (kc2 << 6) + (hi << 4);
#pragma unroll
            for (int rg = 0; rg < 4; ++rg) {
                int row = (rg << 4) + lo;
                short8 a = *(const short8*)(hT + ((row * 256 + (cb ^ ((row & 7) << 4))) >> 1));
                accP[rg][0] = __builtin_amdgcn_mfma_f32_16x16x32_bf16(a, wB[(kc2 << 1) + 0], accP[rg][0], 0, 0, 0);
                accP[rg][1] = __builtin_amdgcn_mfma_f32_16x16x32_bf16(a, wB[(kc2 << 1) + 1], accP[rg][1], 0, 0, 0);
            }
        }
    }

    // ---- masked squared error + reduction
    float s = 0.f;
#pragma unroll
    for (int nt = 0; nt < 2; ++nt) {
        int col = (w << 5) + (nt << 4) + lo;
        float bb = b2s[col] - tgte[col];
#pragma unroll
        for (int rg = 0; rg < 4; ++rg) {
#pragma unroll
            for (int r = 0; r < 4; ++r) {
                int row = (rg << 4) + (hi << 2) + r;   // C/D: col=lane&15, row=(lane>>4)*4+r
                float d = accP[rg][nt][r] + bb;
                if (k0 + row < cnt) s += d * d;
            }
        }
    }
#pragma unroll
    for (int off = 32; off > 0; off >>= 1) s += __shfl_xor(s, off, 64);
    if (l == 0) red[w] = s;
    __syncthreads();
    if (tid == 0) {
        float tot = (red[0] + red[1] + red[2] + red[3]) / ((float)cnt * 128.0f);
        atomicAdd(out, tot);
    }
}

extern "C" void kernel_launch(void* const* d_in, const int* in_sizes, int n_in,
                              void* d_out, int out_size, void* d_ws, size_t ws_size,
                              hipStream_t stream) {
    const float* pe           = (const float*)d_in[0];
    const float* ctx          = (const float*)d_in[1];
    const float* tgt_emb      = (const float*)d_in[2];
    const int*   sub_nodes    = (const int*)d_in[3];
    const int*   sub_counts   = (const int*)d_in[4];
    const int*   target_nodes = (const int*)d_in[5];
    const float* z            = (const float*)d_in[6];
    const float* wpe          = (const float*)d_in[7];
    const float* W1           = (const float*)d_in[8];
    const float* b1           = (const float*)d_in[9];
    const float* W2           = (const float*)d_in[10];
    const float* b2           = (const float*)d_in[11];
    float* out = (float*)d_out;

    char* ws = (char*)d_ws;
    unsigned short* ctx_bf = (unsigned short*)ws;                              // 25.6 MB
    unsigned short* zpe_bf = (unsigned short*)(ws + 25600000);                 // 25.6 MB
    unsigned short* w1p    = (unsigned short*)(ws + 51200000);                 // 256 KB
    unsigned short* w2p    = (unsigned short*)(ws + 51200000 + 262144);        // 128 KB
    float*          ct_g   = (float*)(ws + 51200000 + 262144 + 131072);        // 2 MB

    hipMemsetAsync(d_out, 0, sizeof(float), stream);
    prep_tables<<<(NN * 16 + 255) / 256, 256, 0, stream>>>(pe, ctx, z, wpe, ctx_bf, zpe_bf);
    pack_ct<<<896, 256, 0, stream>>>(W1, W2, pe, z, wpe, target_nodes, b1, w1p, w2p, ct_g);
    mp_jepa_main<<<TT * 4, 256, 0, stream>>>(ctx_bf, zpe_bf, w1p, w2p, ct_g, tgt_emb,
                                             sub_nodes, sub_counts, target_nodes, b2, out);
}